// Round 11
// baseline (156.326 us; speedup 1.0000x reference)
//
#include <hip/hip_runtime.h>
#include <math.h>

typedef float vfloat4 __attribute__((ext_vector_type(4)));

// ---------------- compile-time J tables (reference _np_J, float64) ----------
constexpr double csqrt(double a) {
    double x = a > 1.0 ? a : 1.0;
    for (int i = 0; i < 48; ++i) x = 0.5 * (x + a / x);
    return x;
}

constexpr double j_entry_d(int ell, int mi, int mpi) {
    if (ell == 0) return 1.0;
    double fact[8] = {1.0, 1.0, 2.0, 6.0, 24.0, 120.0, 720.0, 5040.0};
    int m  = ell - mi;
    int mp = ell - mpi;
    double pref  = csqrt(fact[ell + m] * fact[ell - m] * fact[ell + mp] * fact[ell - mp]);
    double scale = 1.0 / (double)(1 << ell);
    int k0 = (m - mp) > 0 ? (m - mp) : 0;
    int k1 = (ell + m) < (ell - mp) ? (ell + m) : (ell - mp);
    double val = 0.0;
    for (int k = k0; k <= k1; ++k) {
        double denom = fact[ell + m - k] * fact[ell - mp - k] * fact[k + mp - m] * fact[k];
        double t = pref / denom * scale;
        val += ((m - mp + k) & 1) ? -t : t;
    }
    return (mi & 1) ? -val : val;
}

// Per-ROW constants (16 rows of the 16x16 block-diag matrix).
struct alignas(16) RowTabs { float t[16][68]; };

constexpr RowTabs make_tabs() {
    RowTabs T{};
    for (int il = 0; il < 16; ++il) {
        int L  = (il == 0) ? 0 : (il < 4) ? 1 : (il < 9) ? 2 : 3;
        int li = il - L * L;
        int m_i = L - li;
        int am  = m_i < 0 ? -m_i : m_i;
        double sgn = (m_i < 0) ? -1.0 : 1.0;
        for (int s = 0; s < 7; ++s) {
            int ms  = 3 - s;
            int ams = ms < 0 ? -ms : ms;
            bool in = (ams <= L);
            int  kp = L - ms;
            T.t[il][s]     = in ? (float)j_entry_d(L, li, kp) : 0.0f;
            T.t[il][7 + s] = in ? (float)(sgn * j_entry_d(L, 2 * L - li, kp)) : 0.0f;
            for (int v = 0; v < 7; ++v)
                T.t[il][14 + 7 * s + v] =
                    (in && v <= 2 * L) ? (float)j_entry_d(L, kp, v) : 0.0f;
        }
        T.t[il][63] = (am == 0) ? 1.0f : 0.0f;
        T.t[il][64] = (am == 1) ? 1.0f : 0.0f;
        T.t[il][65] = (am == 2) ? 1.0f : 0.0f;
        T.t[il][66] = (am == 3) ? 1.0f : 0.0f;
        T.t[il][67] = 0.0f;
    }
    return T;
}

__device__ constexpr RowTabs g_tabs = make_tabs();

// -------- DIAGNOSTIC: fill-identical pure store sweep (writes zeros) --------
// Measures the raw achievable store BW of our launch configuration with zero
// compute/LDS/load coupling. Output is overwritten by the real kernel after.
__global__ __launch_bounds__(256)
void probe_store(float* __restrict__ out, long long n4) {
    long long gid    = (long long)blockIdx.x * 256 + threadIdx.x;
    long long stride = (long long)gridDim.x * 256;
    vfloat4 zz; zz.x = 0.f; zz.y = 0.f; zz.z = 0.f; zz.w = 0.f;
    for (long long i = gid; i < n4; i += stride)
        reinterpret_cast<vfloat4*>(out)[i] = zz;
}

// -------- best-known kernel (R7): 4 edges/wave, LDS transpose, nt stores ----
__global__ __launch_bounds__(256, 4)
void EdgeRotation_49435073577214_kernel(const float* __restrict__ ev,
                                        float* __restrict__ out,
                                        int E, int nwaves) {
    __shared__ float lds[4][1024];          // 4 waves/block x (4 edges x 256 f)

    const int tid  = (int)threadIdx.x;
    const int lane = tid & 63;
    const int wib  = tid >> 6;
    const int g    = lane >> 4;             // edge within quad
    const int il   = lane & 15;             // output row
    float* wlds = lds[wib];

    const int gw = (int)blockIdx.x * 4 + wib;   // global wave id

    // per-row constants -> registers (one-time)
    float jmu[7], jrv[7], M[7][7], sA0, sA1, sA2, sA3;
    {
        const float* tp = g_tabs.t[il];
#pragma unroll
        for (int s = 0; s < 7; ++s) { jmu[s] = tp[s]; jrv[s] = tp[7 + s]; }
#pragma unroll
        for (int s = 0; s < 7; ++s)
#pragma unroll
            for (int v = 0; v < 7; ++v) M[s][v] = tp[14 + 7 * s + v];
        sA0 = tp[63]; sA1 = tp[64]; sA2 = tp[65]; sA3 = tp[66];
    }
    const int LL = (il == 0) ? 0 : (il < 4) ? 1 : (il < 9) ? 4 : 9;  // L^2
    float* pS = wlds + g * 256 + il * 16 + LL;   // scatter base for this lane

    // one-time zero-fill of this wave's 4KB (same-wave LDS ops are in-order)
    {
        vfloat4 zz; zz.x = 0.f; zz.y = 0.f; zz.z = 0.f; zz.w = 0.f;
        vfloat4* wv4 = reinterpret_cast<vfloat4*>(wlds);
        wv4[lane]       = zz;
        wv4[lane + 64]  = zz;
        wv4[lane + 128] = zz;
        wv4[lane + 192] = zz;
    }

    const int Em1 = E - 1;
    const vfloat4* rv4 = reinterpret_cast<const vfloat4*>(wlds);

    for (int e0 = 4 * gw; e0 < E; e0 += 4 * nwaves) {
        int eg = e0 + g;
        eg = eg < E ? eg : Em1;                  // clamp (E%4==0 -> no-op)

        const float x = ev[3 * eg], y = ev[3 * eg + 1], z = ev[3 * eg + 2];

        // ---- angles (amortized over 4 edges/wave) ----
        const float xx   = x * x;
        const float r2   = fmaf(z, z, fmaf(y, y, xx));
        const float rho2 = fmaf(y, y, xx);
        const float rinv = __builtin_amdgcn_rsqf(fmaxf(r2, 1e-30f));
        float cbv = z * rinv;
        cbv = fminf(fmaxf(cbv, -1.0f + 1e-7f), 1.0f - 1e-7f);
        const float sbv = __builtin_amdgcn_sqrtf(fmaxf(fmaf(-cbv, cbv, 1.0f), 0.0f));
        const float rhoinv = __builtin_amdgcn_rsqf(fmaxf(rho2, 1e-30f));
        const bool  ndg = rho2 >= 1e-14f;
        const float ca1 = ndg ? x * rhoinv : 1.0f;
        const float sa1 = ndg ? y * rhoinv : 0.0f;

        const float CA2 = fmaf(ca1, ca1, -(sa1 * sa1));
        const float SA2 = 2.0f * ca1 * sa1;
        const float CA3 = fmaf(CA2, ca1, -(SA2 * sa1));
        const float SA3 = fmaf(SA2, ca1, CA2 * sa1);
        const float CB2 = fmaf(cbv, cbv, -(sbv * sbv));
        const float SB2 = 2.0f * cbv * sbv;
        const float CB3 = fmaf(CB2, cbv, -(SB2 * sbv));
        const float SB3 = fmaf(SB2, cbv, CB2 * sbv);

        // cos/sin(|m_i| alpha) via per-lane multiplicative masks
        float ca = fmaf(sA1, ca1, sA0);
        ca = fmaf(sA2, CA2, ca);
        ca = fmaf(sA3, CA3, ca);
        float sa = sA1 * sa1;
        sa = fmaf(sA2, SA2, sa);
        sa = fmaf(sA3, SA3, sa);                 // sign(m_i) folded into jrv

        float u[7];
#pragma unroll
        for (int s = 0; s < 7; ++s) u[s] = fmaf(ca, jmu[s], sa * jrv[s]);

        float w[7];
        w[0] = fmaf(-u[6], SB3, u[0] * CB3);
        w[1] = fmaf(-u[5], SB2, u[1] * CB2);
        w[2] = fmaf(-u[4], sbv, u[2] * cbv);
        w[3] = u[3];
        w[4] = fmaf( u[2], sbv, u[4] * cbv);
        w[5] = fmaf( u[1], SB2, u[5] * CB2);
        w[6] = fmaf( u[0], SB3, u[6] * CB3);

        // ---- scatter 7 row values (fixed offsets; zeros persist) ----
#pragma unroll
        for (int v = 0; v < 7; ++v) {
            float d = 0.f;
#pragma unroll
            for (int s = 0; s < 7; ++s) d = fmaf(w[s], M[s][v], d);
            pS[v] = d;
        }

        // ---- dense read-back + 4 contiguous 1KB nt stores ----
        if (e0 + 4 <= E) {
#pragma unroll
            for (int q = 0; q < 4; ++q) {
                vfloat4 o = rv4[q * 64 + lane];
                __builtin_nontemporal_store(o,
                    reinterpret_cast<vfloat4*>(out) + (size_t)(e0 + q) * 64 + lane);
            }
        } else {
#pragma unroll
            for (int q = 0; q < 4; ++q) {
                if (e0 + q < E) {
                    vfloat4 o = rv4[q * 64 + lane];
                    __builtin_nontemporal_store(o,
                        reinterpret_cast<vfloat4*>(out) + (size_t)(e0 + q) * 64 + lane);
                }
            }
        }
    }
}

extern "C" void kernel_launch(void* const* d_in, const int* in_sizes, int n_in,
                              void* d_out, int out_size, void* d_ws, size_t ws_size,
                              hipStream_t stream) {
    const float* ev  = (const float*)d_in[0];
    float*       out = (float*)d_out;
    int E = in_sizes[0] / 3;   // [E,3] flat

    // Dispatch 1: diagnostic pure-store sweep (zeros; overwritten below).
    long long n4 = (long long)out_size / 4;
    hipLaunchKernelGGL(probe_store, dim3(2048), dim3(256), 0, stream, out, n4);

    // Dispatch 2: real kernel (correct output).
    dim3 grid(2048), block(256);
    int nwaves = (int)((2048 * 256) / 64);
    hipLaunchKernelGGL(EdgeRotation_49435073577214_kernel, grid, block, 0, stream,
                       ev, out, E, nwaves);
}

// Round 12
// 85.246 us; speedup vs baseline: 1.8338x; 1.8338x over previous
//
#include <hip/hip_runtime.h>
#include <math.h>

typedef float vfloat4 __attribute__((ext_vector_type(4)));

// ---------------- compile-time J tables (reference _np_J, float64) ----------
constexpr double csqrt(double a) {
    double x = a > 1.0 ? a : 1.0;
    for (int i = 0; i < 48; ++i) x = 0.5 * (x + a / x);
    return x;
}

constexpr double j_entry_d(int ell, int mi, int mpi) {
    if (ell == 0) return 1.0;
    double fact[8] = {1.0, 1.0, 2.0, 6.0, 24.0, 120.0, 720.0, 5040.0};
    int m  = ell - mi;
    int mp = ell - mpi;
    double pref  = csqrt(fact[ell + m] * fact[ell - m] * fact[ell + mp] * fact[ell - mp]);
    double scale = 1.0 / (double)(1 << ell);
    int k0 = (m - mp) > 0 ? (m - mp) : 0;
    int k1 = (ell + m) < (ell - mp) ? (ell + m) : (ell - mp);
    double val = 0.0;
    for (int k = k0; k <= k1; ++k) {
        double denom = fact[ell + m - k] * fact[ell - mp - k] * fact[k + mp - m] * fact[k];
        double t = pref / denom * scale;
        val += ((m - mp + k) & 1) ? -t : t;
    }
    return (mi & 1) ? -val : val;
}

// Per-ROW constants (16 rows of the 16x16 block-diag matrix).
struct alignas(16) RowTabs { float t[16][68]; };

constexpr RowTabs make_tabs() {
    RowTabs T{};
    for (int il = 0; il < 16; ++il) {
        int L  = (il == 0) ? 0 : (il < 4) ? 1 : (il < 9) ? 2 : 3;
        int li = il - L * L;
        int m_i = L - li;
        int am  = m_i < 0 ? -m_i : m_i;
        double sgn = (m_i < 0) ? -1.0 : 1.0;
        for (int s = 0; s < 7; ++s) {
            int ms  = 3 - s;
            int ams = ms < 0 ? -ms : ms;
            bool in = (ams <= L);
            int  kp = L - ms;
            T.t[il][s]     = in ? (float)j_entry_d(L, li, kp) : 0.0f;
            T.t[il][7 + s] = in ? (float)(sgn * j_entry_d(L, 2 * L - li, kp)) : 0.0f;
            for (int v = 0; v < 7; ++v)
                T.t[il][14 + 7 * s + v] =
                    (in && v <= 2 * L) ? (float)j_entry_d(L, kp, v) : 0.0f;
        }
        T.t[il][63] = (am == 0) ? 1.0f : 0.0f;
        T.t[il][64] = (am == 1) ? 1.0f : 0.0f;
        T.t[il][65] = (am == 2) ? 1.0f : 0.0f;
        T.t[il][66] = (am == 3) ? 1.0f : 0.0f;
        T.t[il][67] = 0.0f;
    }
    return T;
}

__device__ constexpr RowTabs g_tabs = make_tabs();

#define MAX_IT 16   // max quad-iterations per wave (covers E<=4*nwaves*16)

// 4 edges/wave/iteration, 16 lanes/edge. Changes vs R7 (both target the
// store-counter coupling the R11 probe isolated):
//  (a) ALL coord loads hoisted into a one-time LDS staging pass -> the main
//      loop has ZERO VMEM loads; vmcnt counts only stores, so no load-wait
//      ever forces prior-store retirement.
//  (b) 2-deep buffer rotation (A/B LDS halves + distinct store regs via
//      manual 2x unroll) -> register-WAR waits tolerate 4 outstanding
//      stores (one full iteration of slack) instead of 0.
__global__ __launch_bounds__(256, 4)
void EdgeRotation_49435073577214_kernel(const float* __restrict__ ev,
                                        float* __restrict__ out,
                                        int E, int nwaves) {
    __shared__ float ldsD[4][2048];           // per wave: 2 quad buffers
    __shared__ float ldsC[4][12 * MAX_IT];    // per wave: staged coords

    const int tid  = (int)threadIdx.x;
    const int lane = tid & 63;
    const int wib  = tid >> 6;
    const int g    = lane >> 4;               // edge within quad
    const int il   = lane & 15;               // output row
    float* wlds = ldsD[wib];
    float* wcrd = ldsC[wib];

    const int gw = (int)blockIdx.x * 4 + wib; // global wave id

    // iterations this wave owns
    const int span = 4 * nwaves;
    int nit = 0;
    if (4 * gw < E) nit = (E - 4 * gw + span - 1) / span;

    // ---- one-time coord staging: wave's whole slice -> LDS ----
    const int ncf = nit * 12;
    for (int t = lane; t < ncf; t += 64) {
        const int it = t / 12, j = t - 12 * it;
        const long long fidx = 3LL * (4 * gw + (long long)span * it) + j;
        wcrd[t] = (fidx < 3LL * E) ? ev[fidx] : 0.0f;   // tail-safe (0s benign)
    }

    // per-row constants -> registers (one-time)
    float jmu[7], jrv[7], M[7][7], sA0, sA1, sA2, sA3;
    {
        const float* tp = g_tabs.t[il];
#pragma unroll
        for (int s = 0; s < 7; ++s) { jmu[s] = tp[s]; jrv[s] = tp[7 + s]; }
#pragma unroll
        for (int s = 0; s < 7; ++s)
#pragma unroll
            for (int v = 0; v < 7; ++v) M[s][v] = tp[14 + 7 * s + v];
        sA0 = tp[63]; sA1 = tp[64]; sA2 = tp[65]; sA3 = tp[66];
    }
    const int LL = (il == 0) ? 0 : (il < 4) ? 1 : (il < 9) ? 4 : 9;  // L^2
    float* pS = wlds + g * 256 + il * 16 + LL;   // scatter base (parity 0)

    // one-time zero-fill of both parity buffers (same-wave LDS is in-order)
    {
        vfloat4 zz; zz.x = 0.f; zz.y = 0.f; zz.z = 0.f; zz.w = 0.f;
        vfloat4* wv4 = reinterpret_cast<vfloat4*>(wlds);
#pragma unroll
        for (int q = 0; q < 8; ++q) wv4[lane + 64 * q] = zz;
    }

    const vfloat4* rv4 = reinterpret_cast<const vfloat4*>(wlds);

#define BODY(ITV, PAR)                                                         \
    do {                                                                       \
        const int e0 = 4 * gw + span * (ITV);                                  \
        const float x = wcrd[(ITV) * 12 + 3 * g + 0];                          \
        const float y = wcrd[(ITV) * 12 + 3 * g + 1];                          \
        const float z = wcrd[(ITV) * 12 + 3 * g + 2];                          \
        const float xx   = x * x;                                              \
        const float r2   = fmaf(z, z, fmaf(y, y, xx));                         \
        const float rho2 = fmaf(y, y, xx);                                     \
        const float rinv = __builtin_amdgcn_rsqf(fmaxf(r2, 1e-30f));           \
        float cbv = z * rinv;                                                  \
        cbv = fminf(fmaxf(cbv, -1.0f + 1e-7f), 1.0f - 1e-7f);                  \
        const float sbv =                                                      \
            __builtin_amdgcn_sqrtf(fmaxf(fmaf(-cbv, cbv, 1.0f), 0.0f));        \
        const float rhoinv = __builtin_amdgcn_rsqf(fmaxf(rho2, 1e-30f));       \
        const bool  ndg = rho2 >= 1e-14f;                                      \
        const float ca1 = ndg ? x * rhoinv : 1.0f;                             \
        const float sa1 = ndg ? y * rhoinv : 0.0f;                             \
        const float CA2 = fmaf(ca1, ca1, -(sa1 * sa1));                        \
        const float SA2 = 2.0f * ca1 * sa1;                                    \
        const float CA3 = fmaf(CA2, ca1, -(SA2 * sa1));                        \
        const float SA3 = fmaf(SA2, ca1, CA2 * sa1);                           \
        const float CB2 = fmaf(cbv, cbv, -(sbv * sbv));                        \
        const float SB2 = 2.0f * cbv * sbv;                                    \
        const float CB3 = fmaf(CB2, cbv, -(SB2 * sbv));                        \
        const float SB3 = fmaf(SB2, cbv, CB2 * sbv);                           \
        float ca = fmaf(sA1, ca1, sA0);                                        \
        ca = fmaf(sA2, CA2, ca);                                               \
        ca = fmaf(sA3, CA3, ca);                                               \
        float sa = sA1 * sa1;                                                  \
        sa = fmaf(sA2, SA2, sa);                                               \
        sa = fmaf(sA3, SA3, sa);                                               \
        float u[7];                                                            \
        _Pragma("unroll")                                                      \
        for (int s = 0; s < 7; ++s) u[s] = fmaf(ca, jmu[s], sa * jrv[s]);      \
        float w[7];                                                            \
        w[0] = fmaf(-u[6], SB3, u[0] * CB3);                                   \
        w[1] = fmaf(-u[5], SB2, u[1] * CB2);                                   \
        w[2] = fmaf(-u[4], sbv, u[2] * cbv);                                   \
        w[3] = u[3];                                                           \
        w[4] = fmaf( u[2], sbv, u[4] * cbv);                                   \
        w[5] = fmaf( u[1], SB2, u[5] * CB2);                                   \
        w[6] = fmaf( u[0], SB3, u[6] * CB3);                                   \
        _Pragma("unroll")                                                      \
        for (int v = 0; v < 7; ++v) {                                          \
            float d = 0.f;                                                     \
            _Pragma("unroll")                                                  \
            for (int s = 0; s < 7; ++s) d = fmaf(w[s], M[s][v], d);            \
            pS[(PAR) * 1024 + v] = d;                                          \
        }                                                                      \
        if (e0 + 4 <= E) {                                                     \
            _Pragma("unroll")                                                  \
            for (int q = 0; q < 4; ++q) {                                      \
                vfloat4 o = rv4[(PAR) * 256 + q * 64 + lane];                  \
                __builtin_nontemporal_store(o,                                 \
                    reinterpret_cast<vfloat4*>(out) +                          \
                    (size_t)(e0 + q) * 64 + lane);                             \
            }                                                                  \
        } else {                                                               \
            _Pragma("unroll")                                                  \
            for (int q = 0; q < 4; ++q) {                                      \
                if (e0 + q < E) {                                              \
                    vfloat4 o = rv4[(PAR) * 256 + q * 64 + lane];              \
                    __builtin_nontemporal_store(o,                             \
                        reinterpret_cast<vfloat4*>(out) +                      \
                        (size_t)(e0 + q) * 64 + lane);                         \
                }                                                              \
            }                                                                  \
        }                                                                      \
    } while (0)

    int it = 0;
    for (; it + 2 <= nit; it += 2) {
        BODY(it, 0);
        BODY(it + 1, 1);
    }
    if (it < nit) BODY(it, 0);

#undef BODY
}

extern "C" void kernel_launch(void* const* d_in, const int* in_sizes, int n_in,
                              void* d_out, int out_size, void* d_ws, size_t ws_size,
                              hipStream_t stream) {
    const float* ev  = (const float*)d_in[0];
    float*       out = (float*)d_out;
    int E = in_sizes[0] / 3;   // [E,3] flat

    dim3 grid(2048), block(256);
    int nwaves = (int)((2048 * 256) / 64);   // 8192 waves -> nit <= 13 < MAX_IT
    hipLaunchKernelGGL(EdgeRotation_49435073577214_kernel, grid, block, 0, stream,
                       ev, out, E, nwaves);
}

// Round 13
// 82.171 us; speedup vs baseline: 1.9024x; 1.0374x over previous
//
#include <hip/hip_runtime.h>
#include <math.h>

typedef float vfloat4 __attribute__((ext_vector_type(4)));

// ---------------- compile-time J tables (reference _np_J, float64) ----------
constexpr double csqrt(double a) {
    double x = a > 1.0 ? a : 1.0;
    for (int i = 0; i < 48; ++i) x = 0.5 * (x + a / x);
    return x;
}

constexpr double j_entry_d(int ell, int mi, int mpi) {
    if (ell == 0) return 1.0;
    double fact[8] = {1.0, 1.0, 2.0, 6.0, 24.0, 120.0, 720.0, 5040.0};
    int m  = ell - mi;
    int mp = ell - mpi;
    double pref  = csqrt(fact[ell + m] * fact[ell - m] * fact[ell + mp] * fact[ell - mp]);
    double scale = 1.0 / (double)(1 << ell);
    int k0 = (m - mp) > 0 ? (m - mp) : 0;
    int k1 = (ell + m) < (ell - mp) ? (ell + m) : (ell - mp);
    double val = 0.0;
    for (int k = k0; k <= k1; ++k) {
        double denom = fact[ell + m - k] * fact[ell - mp - k] * fact[k + mp - m] * fact[k];
        double t = pref / denom * scale;
        val += ((m - mp + k) & 1) ? -t : t;
    }
    return (mi & 1) ? -val : val;
}

// Per-ROW constants (16 rows of the 16x16 block-diag matrix).
// Row il: L, li = il - L^2, m_i = L - li. 7-slot m-frame, slot s <-> m_s = 3-s.
// [0..6]   jmu[s]  = J_L[li,   L-m_s]                 (0 outside block)
// [7..13]  jrv[s]  = sign(m_i)*J_L[2L-li, L-m_s]      (alpha sign pre-folded)
// [14..62] M[s][v] = J_L[L-m_s, v], v=0..6            (0 outside block)
// [63..66] sA0..sA3 multiplicative masks for |m_i| == 0..3
struct alignas(16) RowTabs { float t[16][68]; };

constexpr RowTabs make_tabs() {
    RowTabs T{};
    for (int il = 0; il < 16; ++il) {
        int L  = (il == 0) ? 0 : (il < 4) ? 1 : (il < 9) ? 2 : 3;
        int li = il - L * L;
        int m_i = L - li;
        int am  = m_i < 0 ? -m_i : m_i;
        double sgn = (m_i < 0) ? -1.0 : 1.0;
        for (int s = 0; s < 7; ++s) {
            int ms  = 3 - s;
            int ams = ms < 0 ? -ms : ms;
            bool in = (ams <= L);
            int  kp = L - ms;
            T.t[il][s]     = in ? (float)j_entry_d(L, li, kp) : 0.0f;
            T.t[il][7 + s] = in ? (float)(sgn * j_entry_d(L, 2 * L - li, kp)) : 0.0f;
            for (int v = 0; v < 7; ++v)
                T.t[il][14 + 7 * s + v] =
                    (in && v <= 2 * L) ? (float)j_entry_d(L, kp, v) : 0.0f;
        }
        T.t[il][63] = (am == 0) ? 1.0f : 0.0f;
        T.t[il][64] = (am == 1) ? 1.0f : 0.0f;
        T.t[il][65] = (am == 2) ? 1.0f : 0.0f;
        T.t[il][66] = (am == 3) ? 1.0f : 0.0f;
        T.t[il][67] = 0.0f;
    }
    return T;
}

__device__ constexpr RowTabs g_tabs = make_tabs();

// 4 edges per wave, 16 lanes per edge. Lane (g = lane>>4, il = lane&15)
// computes row il of edge e0+g (7 block values), scatters into a wave-private
// 4KB LDS region, then the wave reads back densely and issues 4 contiguous
// 1KB nt stores. Same-wave LDS ops are in-order -> no barriers.
// Zero slots in LDS are initialized ONCE: the scatter hits the same 7 offsets
// every iteration, so untouched slots stay zero for the whole kernel.
__global__ __launch_bounds__(256, 4)
void EdgeRotation_49435073577214_kernel(const float* __restrict__ ev,
                                        float* __restrict__ out,
                                        int E, int nwaves) {
    __shared__ float lds[4][1024];          // 4 waves/block x (4 edges x 256 f)

    const int tid  = (int)threadIdx.x;
    const int lane = tid & 63;
    const int wib  = tid >> 6;
    const int g    = lane >> 4;             // edge within quad
    const int il   = lane & 15;             // output row
    float* wlds = lds[wib];

    const int gw = (int)blockIdx.x * 4 + wib;   // global wave id

    // per-row constants -> registers (one-time)
    float jmu[7], jrv[7], M[7][7], sA0, sA1, sA2, sA3;
    {
        const float* tp = g_tabs.t[il];
#pragma unroll
        for (int s = 0; s < 7; ++s) { jmu[s] = tp[s]; jrv[s] = tp[7 + s]; }
#pragma unroll
        for (int s = 0; s < 7; ++s)
#pragma unroll
            for (int v = 0; v < 7; ++v) M[s][v] = tp[14 + 7 * s + v];
        sA0 = tp[63]; sA1 = tp[64]; sA2 = tp[65]; sA3 = tp[66];
    }
    const int LL = (il == 0) ? 0 : (il < 4) ? 1 : (il < 9) ? 4 : 9;  // L^2
    float* pS = wlds + g * 256 + il * 16 + LL;   // scatter base for this lane

    // one-time zero-fill of this wave's 4KB (same-wave LDS ops are in-order,
    // so the first iteration's scatter safely lands after these writes)
    {
        vfloat4 zz; zz.x = 0.f; zz.y = 0.f; zz.z = 0.f; zz.w = 0.f;
        vfloat4* wv4 = reinterpret_cast<vfloat4*>(wlds);
        wv4[lane]       = zz;
        wv4[lane + 64]  = zz;
        wv4[lane + 128] = zz;
        wv4[lane + 192] = zz;
    }

    const int Em1 = E - 1;
    const vfloat4* rv4 = reinterpret_cast<const vfloat4*>(wlds);

    for (int e0 = 4 * gw; e0 < E; e0 += 4 * nwaves) {
        int eg = e0 + g;
        eg = eg < E ? eg : Em1;                  // clamp (E%4==0 -> no-op)

        const float x = ev[3 * eg], y = ev[3 * eg + 1], z = ev[3 * eg + 2];

        // ---- angles (amortized over 4 edges/wave) ----
        const float xx   = x * x;
        const float r2   = fmaf(z, z, fmaf(y, y, xx));
        const float rho2 = fmaf(y, y, xx);
        const float rinv = __builtin_amdgcn_rsqf(fmaxf(r2, 1e-30f));
        float cbv = z * rinv;
        cbv = fminf(fmaxf(cbv, -1.0f + 1e-7f), 1.0f - 1e-7f);
        const float sbv = __builtin_amdgcn_sqrtf(fmaxf(fmaf(-cbv, cbv, 1.0f), 0.0f));
        const float rhoinv = __builtin_amdgcn_rsqf(fmaxf(rho2, 1e-30f));
        const bool  ndg = rho2 >= 1e-14f;
        const float ca1 = ndg ? x * rhoinv : 1.0f;
        const float sa1 = ndg ? y * rhoinv : 0.0f;

        const float CA2 = fmaf(ca1, ca1, -(sa1 * sa1));
        const float SA2 = 2.0f * ca1 * sa1;
        const float CA3 = fmaf(CA2, ca1, -(SA2 * sa1));
        const float SA3 = fmaf(SA2, ca1, CA2 * sa1);
        const float CB2 = fmaf(cbv, cbv, -(sbv * sbv));
        const float SB2 = 2.0f * cbv * sbv;
        const float CB3 = fmaf(CB2, cbv, -(SB2 * sbv));
        const float SB3 = fmaf(SB2, cbv, CB2 * sbv);

        // cos/sin(|m_i| alpha) via per-lane multiplicative masks
        float ca = fmaf(sA1, ca1, sA0);
        ca = fmaf(sA2, CA2, ca);
        ca = fmaf(sA3, CA3, ca);
        float sa = sA1 * sa1;
        sa = fmaf(sA2, SA2, sa);
        sa = fmaf(sA3, SA3, sa);                 // sign(m_i) folded into jrv

        float u[7];
#pragma unroll
        for (int s = 0; s < 7; ++s) u[s] = fmaf(ca, jmu[s], sa * jrv[s]);

        float w[7];
        w[0] = fmaf(-u[6], SB3, u[0] * CB3);
        w[1] = fmaf(-u[5], SB2, u[1] * CB2);
        w[2] = fmaf(-u[4], sbv, u[2] * cbv);
        w[3] = u[3];
        w[4] = fmaf( u[2], sbv, u[4] * cbv);
        w[5] = fmaf( u[1], SB2, u[5] * CB2);
        w[6] = fmaf( u[0], SB3, u[6] * CB3);

        // ---- scatter 7 row values (fixed offsets; zeros persist) ----
#pragma unroll
        for (int v = 0; v < 7; ++v) {
            float d = 0.f;
#pragma unroll
            for (int s = 0; s < 7; ++s) d = fmaf(w[s], M[s][v], d);
            pS[v] = d;
        }

        // ---- dense read-back + 4 contiguous 1KB nt stores ----
        if (e0 + 4 <= E) {
#pragma unroll
            for (int q = 0; q < 4; ++q) {
                vfloat4 o = rv4[q * 64 + lane];
                __builtin_nontemporal_store(o,
                    reinterpret_cast<vfloat4*>(out) + (size_t)(e0 + q) * 64 + lane);
            }
        } else {
#pragma unroll
            for (int q = 0; q < 4; ++q) {
                if (e0 + q < E) {
                    vfloat4 o = rv4[q * 64 + lane];
                    __builtin_nontemporal_store(o,
                        reinterpret_cast<vfloat4*>(out) + (size_t)(e0 + q) * 64 + lane);
                }
            }
        }
    }
}

extern "C" void kernel_launch(void* const* d_in, const int* in_sizes, int n_in,
                              void* d_out, int out_size, void* d_ws, size_t ws_size,
                              hipStream_t stream) {
    const float* ev  = (const float*)d_in[0];
    float*       out = (float*)d_out;
    int E = in_sizes[0] / 3;   // [E,3] flat

    dim3 grid(2048), block(256);
    int nwaves = (int)((2048 * 256) / 64);
    hipLaunchKernelGGL(EdgeRotation_49435073577214_kernel, grid, block, 0, stream,
                       ev, out, E, nwaves);
}